// Round 3
// baseline (236.910 us; speedup 1.0000x reference)
//
#include <hip/hip_runtime.h>
#include <stdint.h>

typedef unsigned short u16;
typedef __attribute__((ext_vector_type(8))) short short8;
typedef __attribute__((ext_vector_type(4))) float floatx4;
typedef __attribute__((ext_vector_type(2))) float floatx2;

#define K_DIM 1024
#define N_DIM 1024
#define BM 32
#define BK 32
#define NCHUNK (K_DIM / BK)
#define NI 8            // col tiles (of 16) per wave: 8 waves x 128 cols = 1024
#define MI 2            // row tiles (of 16) per block: BM = 32

__device__ __forceinline__ u16 f2b(float f) {
    union { float f; uint32_t i; } v; v.f = f;
    uint32_t u = v.i;
    return (u16)((u + 0x7FFFu + ((u >> 16) & 1u)) >> 16);   // RNE fp32->bf16
}
__device__ __forceinline__ float b2f(u16 u) {
    union { uint32_t i; float f; } v; v.i = ((uint32_t)u) << 16; return v.f;
}

// ---------- kernel 1: W fp32 -> bf16, packed kc-major per 8-tile wave group ----
// dst element offset = wv*131072 + kc*4096 + ni*512 + lane*8, where the source
// fragment is tile t = wv*8 + ni:  W[t*16 + (lane&15)][kc*32 + (lane>>4)*8 + j].
// Per (wave, chunk) the 8 ni fragments are contiguous 8KB -> single base + imm.
__global__ __launch_bounds__(256) void pack_w_kernel(const float* __restrict__ w,
                                                     u16* __restrict__ wpk) {
    int gid  = blockIdx.x * 256 + threadIdx.x;   // 0..131071: (tile,kc,lane)
    int lane = gid & 63;
    int kc   = (gid >> 6) & 31;
    int tile = gid >> 11;                        // 0..63
    int n = tile * 16 + (lane & 15);
    int k = kc * 32 + (lane >> 4) * 8;
    const float* src = w + (size_t)n * K_DIM + k;
    floatx4 a = *(const floatx4*)(src);
    floatx4 b = *(const floatx4*)(src + 4);
    short8 o;
    o[0] = (short)f2b(a[0]); o[1] = (short)f2b(a[1]);
    o[2] = (short)f2b(a[2]); o[3] = (short)f2b(a[3]);
    o[4] = (short)f2b(b[0]); o[5] = (short)f2b(b[1]);
    o[6] = (short)f2b(b[2]); o[7] = (short)f2b(b[3]);
    int wv = tile >> 3, ni = tile & 7;
    size_t dst = (size_t)wv * 131072 + (size_t)kc * 4096 + ni * 512 + lane * 8;
    *(short8*)(wpk + dst) = o;
}

// ---------- kernel 2: fused GEMM + bias + LayerNorm + (ln+y)*y ----------
// 512 threads (8 waves x 128 cols), BM=32, grid=512 -> TWO independent blocks
// per CU (16 waves, ~75KB LDS, <=128 regs/wave). The two blocks are not
// barrier-coupled, so one block's MFMA/L2 phase overlaps the other's HBM
// epilogue and barrier stalls. Raw s_barrier (lgkmcnt only) in the K-loop.
__global__ __launch_bounds__(512, 4) void fused_gemm_ln_kernel(
    const float* __restrict__ x, const float* __restrict__ y,
    const u16* __restrict__ wpk, const float* __restrict__ bias,
    const float* __restrict__ gamma, const float* __restrict__ beta,
    float* __restrict__ out)
{
    __shared__ __align__(16) u16 lds_a[2][BM * BK];   // 2 x 2KB bf16 A tiles, swizzled
    __shared__ __align__(16) u16 zbuf[16 * 1024];     // 32KB bf16 transpose buffer
    __shared__ float ls_sum[BM];
    __shared__ float ls_sum2[BM];
    __shared__ float ls_mean[BM];
    __shared__ float ls_rs[BM];

    const int tid  = threadIdx.x;
    const int lane = tid & 63;
    const int wv   = tid >> 6;            // 0..7
    const int q    = lane >> 4;           // quarter-wave id
    const int row0 = blockIdx.x * BM;

    if (tid < BM) { ls_sum[tid] = 0.0f; ls_sum2[tid] = 0.0f; }

    // ---- A staging (512 threads, 2 fp32 each per chunk: 32 rows x 32 k) ----
    const int sr = tid >> 4;              // 0..31
    const int sk = (tid & 15) << 1;       // even 0..30
    const float* s_src = x + (size_t)(row0 + sr) * K_DIM + sk;
    const int s_qs  = (sk >> 3) ^ ((sr >> 1) & 3);
    const int s_off = sr * 64 + s_qs * 16 + (sk & 7) * 2;

    // ---- B: kc-major packed base; chunk kc frag ni at + kc*4096 + ni*512 elems ----
    const u16* bp = wpk + (size_t)wv * 131072 + lane * 8;

    // ---- A fragment LDS base offset (mi-invariant swizzle) ----
    const int a_base = (lane & 15) * 64 + (q ^ (((lane & 15) >> 1) & 3)) * 16;

    floatx4 acc[MI][NI];
#pragma unroll
    for (int mi = 0; mi < MI; ++mi)
#pragma unroll
        for (int ni = 0; ni < NI; ++ni)
            acc[mi][ni] = (floatx4){0.0f, 0.0f, 0.0f, 0.0f};

    // ---- prologue: stage A chunk0; prefetch A chunks 1,2; B chunk0 ----
    {
        floatx2 v0 = *(const floatx2*)(s_src);
        uint32_t p = (uint32_t)f2b(v0[0]) | ((uint32_t)f2b(v0[1]) << 16);
        *(uint32_t*)((char*)(&lds_a[0][0]) + s_off) = p;
    }
    floatx2 va_next = *(const floatx2*)(s_src + BK);        // chunk 1 (in flight)
    floatx2 va_far  = *(const floatx2*)(s_src + 2 * BK);    // chunk 2 (in flight)

    short8 bfr[NI];                                          // rolling B buffer
#pragma unroll
    for (int ni = 0; ni < NI; ++ni)
        bfr[ni] = *(const short8*)(bp + ni * 512);           // kc=0

#pragma unroll 1
    for (int kc = 0; kc < NCHUNK; ++kc) {
        const int cur = kc & 1;

        // LDS writes visible; global prefetches NOT drained (stay in flight)
        asm volatile("s_waitcnt lgkmcnt(0)" ::: "memory");
        __builtin_amdgcn_s_barrier();
        asm volatile("" ::: "memory");

        // A frags for this chunk from LDS
        short8 afrag[MI];
        const char* ab = (const char*)(&lds_a[cur][0]);
#pragma unroll
        for (int mi = 0; mi < MI; ++mi)
            afrag[mi] = *(const short8*)(ab + a_base + mi * 1024);

        // far A global load (chunk kc+3, clamped) — lands ~2.5 chunks from now
        const int ka = (kc + 3 < NCHUNK) ? (kc + 3) : (NCHUNK - 1);
        floatx2 vnew = *(const floatx2*)(s_src + ka * BK);

        // MFMA + rolling B reload (chunk kc+1, clamped): each frag reloaded
        // right after its last use; load->use distance = ~1 full chunk
        const int kn = (kc + 1 < NCHUNK) ? (kc + 1) : kc;
        const u16* bnext = bp + (size_t)kn * 4096;
#pragma unroll
        for (int ni = 0; ni < NI; ++ni) {
            acc[0][ni] = __builtin_amdgcn_mfma_f32_16x16x32_bf16(
                afrag[0], bfr[ni], acc[0][ni], 0, 0, 0);
            acc[1][ni] = __builtin_amdgcn_mfma_f32_16x16x32_bf16(
                afrag[1], bfr[ni], acc[1][ni], 0, 0, 0);
            bfr[ni] = *(const short8*)(bnext + ni * 512);
        }

        // stage chunk kc+1 from registers (loaded ~2.5 chunks ago), rotate
        {
            uint32_t p = (uint32_t)f2b(va_next[0]) | ((uint32_t)f2b(va_next[1]) << 16);
            *(uint32_t*)((char*)(&lds_a[cur ^ 1][0]) + s_off) = p;
            va_next = va_far;
            va_far  = vnew;
        }
    }

    // ---- epilogue: bias (fp32) ----
    float bias_v[NI];
#pragma unroll
    for (int ni = 0; ni < NI; ++ni)
        bias_v[ni] = bias[(wv << 7) + (ni << 4) + (lane & 15)];
#pragma unroll
    for (int mi = 0; mi < MI; ++mi)
#pragma unroll
        for (int ni = 0; ni < NI; ++ni)
#pragma unroll
            for (int r = 0; r < 4; ++r)
                acc[mi][ni][r] += bias_v[ni];

    // ---- row stats: in-wave 128-col reduce, then LDS float atomics ----
#pragma unroll
    for (int mi = 0; mi < MI; ++mi)
#pragma unroll
        for (int r = 0; r < 4; ++r) {
            float s = 0.0f, s2 = 0.0f;
#pragma unroll
            for (int ni = 0; ni < NI; ++ni) {
                float v = acc[mi][ni][r];
                s += v; s2 += v * v;
            }
#pragma unroll
            for (int m = 1; m < 16; m <<= 1) {
                s  += __shfl_xor(s,  m, 64);
                s2 += __shfl_xor(s2, m, 64);
            }
            if ((lane & 15) == 0) {
                int rl = (mi << 4) + (q << 2) + r;       // local row
                atomicAdd(&ls_sum[rl], s);
                atomicAdd(&ls_sum2[rl], s2);
            }
        }

    __syncthreads();
    if (tid < BM) {
        float mean = ls_sum[tid] * (1.0f / 1024.0f);
        float var  = ls_sum2[tid] * (1.0f / 1024.0f) - mean * mean;
        ls_mean[tid] = mean;
        ls_rs[tid]   = rsqrtf(var + 1e-5f);
    }

    // ---- per 16-row slice: LDS transpose (bf16), coalesced fp32 LN+res+mul ----
    for (int mi = 0; mi < MI; ++mi) {
#pragma unroll
        for (int ni = 0; ni < NI; ++ni)
#pragma unroll
            for (int r = 0; r < 4; ++r) {
                int lr   = (q << 2) + r;                          // local row 0..15
                int lin  = (((wv << 7) + (ni << 4) + (lane & 15)) << 1);
                int phys = lr * 2048 + (lin ^ (q << 5));          // swizzled
                *(u16*)((char*)zbuf + phys) = f2b(acc[mi][ni][r]);
            }
        __syncthreads();
#pragma unroll
        for (int it = 0; it < 4; ++it) {
            int row  = (tid >> 7) + (it << 2);                    // 0..15
            int c8   = tid & 127;                                 // 16B chunk id
            int phys = row * 2048 + ((c8 << 4) ^ (((row >> 2) & 3) << 5));
            short8 z8 = *(const short8*)((const char*)zbuf + phys);
            int grow  = row0 + (mi << 4) + row;
            float mean = ls_mean[(mi << 4) + row];
            float rs   = ls_rs[(mi << 4) + row];
            const float* yp = y     + (size_t)grow * N_DIM + c8 * 8;
            const float* gp = gamma + c8 * 8;
            const float* bpv = beta + c8 * 8;
            float*       op = out   + (size_t)grow * N_DIM + c8 * 8;
            floatx4 y0 = *(const floatx4*)(yp);
            floatx4 y1 = *(const floatx4*)(yp + 4);
            floatx4 g0 = *(const floatx4*)(gp);
            floatx4 g1 = *(const floatx4*)(gp + 4);
            floatx4 b0 = *(const floatx4*)(bpv);
            floatx4 b1 = *(const floatx4*)(bpv + 4);
            floatx4 o0, o1;
#pragma unroll
            for (int e = 0; e < 4; ++e) {
                float zv = b2f((u16)z8[e]);
                o0[e] = ((zv - mean) * rs * g0[e] + b0[e] + y0[e]) * y0[e];
            }
#pragma unroll
            for (int e = 0; e < 4; ++e) {
                float zv = b2f((u16)z8[e + 4]);
                o1[e] = ((zv - mean) * rs * g1[e] + b1[e] + y1[e]) * y1[e];
            }
            *(floatx4*)(op)     = o0;
            *(floatx4*)(op + 4) = o1;
        }
        __syncthreads();
    }
}

extern "C" void kernel_launch(void* const* d_in, const int* in_sizes, int n_in,
                              void* d_out, int out_size, void* d_ws, size_t ws_size,
                              hipStream_t stream) {
    const float* x     = (const float*)d_in[0];
    const float* y     = (const float*)d_in[1];
    const float* wgt   = (const float*)d_in[2];
    const float* bias  = (const float*)d_in[3];
    const float* gamma = (const float*)d_in[4];
    const float* beta  = (const float*)d_in[5];
    float* out = (float*)d_out;
    u16* wpk = (u16*)d_ws;                               // 2MB packed bf16 W

    pack_w_kernel<<<512, 256, 0, stream>>>(wgt, wpk);

    const int M = in_sizes[0] / K_DIM;                   // 16384
    fused_gemm_ln_kernel<<<M / BM, 512, 0, stream>>>(x, y, wpk, bias, gamma, beta, out);
}